// Round 4
// baseline (317.383 us; speedup 1.0000x reference)
//
#include <hip/hip_runtime.h>

#define NB 8
#define NN 2048
#define DF 128
#define NF 128

typedef __attribute__((ext_vector_type(8))) __bf16 bf16x8;
typedef __attribute__((ext_vector_type(4))) float f32x4;
typedef __attribute__((ext_vector_type(8))) unsigned short u16x8;
typedef __attribute__((ext_vector_type(4))) unsigned short u16x4;

__device__ inline unsigned short f2bf(float f) {
    unsigned int u = __float_as_uint(f);
    u += 0x7FFFu + ((u >> 16) & 1u);   // round-to-nearest-even
    return (unsigned short)(u >> 16);
}

// K0: WdT[fo][di] = bf16(W[di][fo]). One-time 32KB transpose; grid 16 x 256.
__global__ __launch_bounds__(256) void k_wt(const float* __restrict__ W,
                                            unsigned short* __restrict__ WdT) {
    int t = threadIdx.x;
    int di  = blockIdx.x * 8 + (t >> 5);
    int fo4 = (t & 31) * 4;
    float4 v = *(const float4*)(W + di * NF + fo4);
    WdT[(fo4 + 0) * DF + di] = f2bf(v.x);
    WdT[(fo4 + 1) * DF + di] = f2bf(v.y);
    WdT[(fo4 + 2) * DF + di] = f2bf(v.z);
    WdT[(fo4 + 3) * DF + di] = f2bf(v.w);
}

// K1: single streaming pass over A:
//   outA = A (fp32 copy), colsum += per-column partials,
//   AbfF  = bf16(A+I) packed FRAGMENT-LINEAR: for (r16, ks) the 16x32 tile is
//           stored as 64 lanes x 16B (lane = q*16+m16 holds A[m16][q*8..+8]),
//           1KB contiguous -> GEMM loads are perfectly coalesced u16x8.
// Grid 8b x 8jt x 16it = 1024 blocks (tile 128 rows x 256 cols), 4 blocks/CU.
__global__ __launch_bounds__(256) void k_stream(const float* __restrict__ A,
                                                float* __restrict__ outA,
                                                unsigned short* __restrict__ AbfF,
                                                float* __restrict__ colsum) {
    __shared__ unsigned short Tb[32 * 264];   // 32-row bf16 subtile, padded
    __shared__ float red[4][256];
    int bid = blockIdx.x;
    int it = bid & 15;
    int jt = (bid >> 4) & 7;
    int b  = bid >> 7;
    int t  = threadIdx.x;
    int jq = t & 63;
    int ir = t >> 6;
    const float*    Ab = A    + (size_t)b * NN * NN;
    float*          Ob = outA + (size_t)b * NN * NN;
    unsigned short* Fb = AbfF + (size_t)b * NN * NN;   // u16 units
    int j0 = jt * 256 + jq * 4;
    float4 s = make_float4(0.f, 0.f, 0.f, 0.f);

    for (int st = 0; st < 4; st++) {          // four 32-row subtiles
        int r0 = it * 128 + st * 32;
#pragma unroll
        for (int p = 0; p < 8; p++) {
            int rl = ir + p * 4;              // 0..31
            int i  = r0 + rl;
            size_t off = (size_t)i * NN + j0;
            float4 v = *(const float4*)(Ab + off);
            *(float4*)(Ob + off) = v;         // fp32 copy rides the read
            s.x += v.x; s.y += v.y; s.z += v.z; s.w += v.w;
            u16x4 u;
            u[0] = f2bf(v.x + ((i == j0 + 0) ? 1.0f : 0.0f));   // +I fused
            u[1] = f2bf(v.y + ((i == j0 + 1) ? 1.0f : 0.0f));
            u[2] = f2bf(v.z + ((i == j0 + 2) ? 1.0f : 0.0f));
            u[3] = f2bf(v.w + ((i == j0 + 3) ? 1.0f : 0.0f));
            *(u16x4*)&Tb[rl * 264 + jq * 4] = u;
        }
        __syncthreads();
        // frag-order readout: 1024 lane-chunks (2 r16 x 8 ks x 64 lanes), 4/thread
#pragma unroll
        for (int rep = 0; rep < 4; rep++) {
            int c    = rep * 256 + t;
            int lane = c & 63;
            int ksl  = (c >> 6) & 7;
            int r16l = c >> 9;                // 0..1
            int q = lane >> 4, m16 = lane & 15;
            u16x8 u = *(const u16x8*)&Tb[(r16l * 16 + m16) * 264 + ksl * 32 + q * 8];
            int r16g = (r0 >> 4) + r16l;
            int ksg  = jt * 8 + ksl;
            *(u16x8*)(Fb + (((size_t)r16g * 64 + ksg) * 64 + lane) * 8) = u;
        }
        __syncthreads();
    }
    *(float4*)&red[ir][jq * 4] = s;
    __syncthreads();
    float v = red[0][t] + red[1][t] + red[2][t] + red[3][t];
    atomicAdd(colsum + b * NN + jt * 256 + t, v);
}

// K2: XdTF = fragment-linear bf16 of Xd^T where Xd[j][n] = rsqrt(1+colsum[j])*X[j][n].
// Layout: [b][c16(8)][ks(64)][lane(64)][8]; frag (c16,ks): lane (q,m16) holds
// Xd[ks*32+q*8 ..+8][c16*16+m16]. Grid 8b x 32jt = 256 blocks.
__global__ __launch_bounds__(256) void k_xdt(const float* __restrict__ X,
                                             const float* __restrict__ colsum,
                                             unsigned short* __restrict__ XdTF) {
    __shared__ unsigned short T[128 * 72];   // [f][j_local 64->72 pad]
    int jt = blockIdx.x & 31;
    int b  = blockIdx.x >> 5;
    int j0 = jt * 64;
    int t = threadIdx.x;
    int r = t >> 5;
    int c = t & 31;
#pragma unroll
    for (int p = 0; p < 8; p++) {
        int j = r + p * 8;
        float dv = rsqrtf(1.0f + colsum[b * NN + j0 + j]);
        float4 v = *(const float4*)(X + ((size_t)(b * NN + j0 + j)) * DF + c * 4);
        T[(c * 4 + 0) * 72 + j] = f2bf(v.x * dv);
        T[(c * 4 + 1) * 72 + j] = f2bf(v.y * dv);
        T[(c * 4 + 2) * 72 + j] = f2bf(v.z * dv);
        T[(c * 4 + 3) * 72 + j] = f2bf(v.w * dv);
    }
    __syncthreads();
    int ks0 = j0 >> 5;                        // 2 ks per block
#pragma unroll
    for (int rep = 0; rep < 4; rep++) {
        int ch   = rep * 256 + t;             // 1024 chunks: 2ks x 8c16 x 64lanes
        int lane = ch & 63;
        int c16  = (ch >> 6) & 7;
        int ksl  = ch >> 9;                   // 0..1
        int q = lane >> 4, m16 = lane & 15;
        u16x8 u = *(const u16x8*)&T[(c16 * 16 + m16) * 72 + ksl * 32 + q * 8];
        *(u16x8*)(XdTF + (((size_t)(b * 8 + c16) * 64 + ks0 + ksl) * 64 + lane) * 8) = u;
    }
}

// K3: pure-MFMA GEMM.  P = (A+I)@Xd from pre-packed frags (zero LDS/stores/
// barriers/converts in K-loop); epilogue: x d_i -> Ps(LDS) -> H = relu(P@W).
// Grid 512 = 8b x 64mt (BM=32), 512 thr = 8 waves (wr 0..1 x wc 0..3),
// 2 blocks/CU -> 16 waves/CU, 4/SIMD. b = bid&7 pins batch b's XdTF to XCD b.
__global__ __launch_bounds__(512, 4) void k_gemm(const unsigned short* __restrict__ AbfF,
                                                 const unsigned short* __restrict__ XdTF,
                                                 const float* __restrict__ colsum,
                                                 const unsigned short* __restrict__ WdT,
                                                 float* __restrict__ H) {
    __shared__ unsigned short Ps[32 * 136];
    int bid = blockIdx.x;
    int b  = bid & 7;
    int mt = bid >> 3;                        // 0..63
    int t = threadIdx.x;
    int w = t >> 6, l = t & 63, m16 = l & 15, q = l >> 4;
    int wr = w >> 2, wc = w & 3;
    const unsigned short* Ab = AbfF + (size_t)b * NN * NN;
    const unsigned short* Xb = XdTF + (size_t)b * 8 * 64 * 512;
    int r16g = mt * 2 + wr;
    const unsigned short* ap = Ab + ((size_t)r16g * 64) * 512 + l * 8;
    const unsigned short* x0 = Xb + ((size_t)(wc * 2 + 0) * 64) * 512 + l * 8;
    const unsigned short* x1 = Xb + ((size_t)(wc * 2 + 1) * 64) * 512 + l * 8;

    f32x4 acc0 = (f32x4){0.f, 0.f, 0.f, 0.f};
    f32x4 acc1 = (f32x4){0.f, 0.f, 0.f, 0.f};
#pragma unroll 4
    for (int ks = 0; ks < 64; ks++) {
        bf16x8 af = __builtin_bit_cast(bf16x8, *(const u16x8*)(ap + ks * 512));
        bf16x8 b0 = __builtin_bit_cast(bf16x8, *(const u16x8*)(x0 + ks * 512));
        bf16x8 b1 = __builtin_bit_cast(bf16x8, *(const u16x8*)(x1 + ks * 512));
        acc0 = __builtin_amdgcn_mfma_f32_16x16x32_bf16(af, b0, acc0, 0, 0, 0);
        acc1 = __builtin_amdgcn_mfma_f32_16x16x32_bf16(af, b1, acc1, 0, 0, 0);
    }

    // epilogue 1: x d_i, pack P tile (bf16) to LDS
    int m0 = mt * 32;
#pragma unroll
    for (int r = 0; r < 4; r++) {
        float dv = rsqrtf(1.0f + colsum[b * NN + m0 + wr * 16 + q * 4 + r]);
        Ps[(wr * 16 + q * 4 + r) * 136 + (wc * 2 + 0) * 16 + m16] = f2bf(acc0[r] * dv);
        Ps[(wr * 16 + q * 4 + r) * 136 + (wc * 2 + 1) * 16 + m16] = f2bf(acc1[r] * dv);
    }
    __syncthreads();

    // epilogue 2: H = relu(P @ W), W B-frags straight from global WdT (L2-hot)
    f32x4 h0 = (f32x4){0.f, 0.f, 0.f, 0.f};
    f32x4 h1 = (f32x4){0.f, 0.f, 0.f, 0.f};
#pragma unroll
    for (int ks = 0; ks < 4; ks++) {
        bf16x8 pa = __builtin_bit_cast(bf16x8,
            *(const u16x8*)&Ps[(wr * 16 + m16) * 136 + ks * 32 + q * 8]);
        bf16x8 w0 = __builtin_bit_cast(bf16x8,
            *(const u16x8*)(WdT + (size_t)(wc * 32 + m16) * DF + ks * 32 + q * 8));
        bf16x8 w1 = __builtin_bit_cast(bf16x8,
            *(const u16x8*)(WdT + (size_t)(wc * 32 + 16 + m16) * DF + ks * 32 + q * 8));
        h0 = __builtin_amdgcn_mfma_f32_16x16x32_bf16(pa, w0, h0, 0, 0, 0);
        h1 = __builtin_amdgcn_mfma_f32_16x16x32_bf16(pa, w1, h1, 0, 0, 0);
    }
#pragma unroll
    for (int r = 0; r < 4; r++) {
        int grow = m0 + wr * 16 + q * 4 + r;
        float v0 = h0[r] > 0.f ? h0[r] : 0.f;
        float v1 = h1[r] > 0.f ? h1[r] : 0.f;
        H[((size_t)(b * NN + grow)) * NF + wc * 32 + m16]      = v0;
        H[((size_t)(b * NN + grow)) * NF + wc * 32 + 16 + m16] = v1;
    }
}

extern "C" void kernel_launch(void* const* d_in, const int* in_sizes, int n_in,
                              void* d_out, int out_size, void* d_ws, size_t ws_size,
                              hipStream_t stream) {
    const float* A = (const float*)d_in[0];
    const float* X = (const float*)d_in[1];
    const float* W = (const float*)d_in[2];
    float* out  = (float*)d_out;
    float* outA = out;
    float* H    = out + (size_t)NB * NN * NN;   // tuple: (A, H) flat

    char* ws = (char*)d_ws;
    float* colsum        = (float*)ws;                                   // 64 KB
    unsigned short* XdTF = (unsigned short*)(ws + (1 << 16));            // 4 MB
    unsigned short* WdT  = (unsigned short*)(ws + (1 << 16) + (4 << 20));          // 32 KB
    unsigned short* AbfF = (unsigned short*)(ws + (1 << 16) + (4 << 20) + (1 << 15)); // 64 MB

    hipMemsetAsync(colsum, 0, 65536, stream);
    k_wt<<<16, 256, 0, stream>>>(W, WdT);
    k_stream<<<1024, 256, 0, stream>>>(A, outA, AbfF, colsum);
    k_xdt<<<256, 256, 0, stream>>>(X, colsum, XdTF);
    k_gemm<<<512, 512, 0, stream>>>(AbfF, XdTF, colsum, WdT, H);
}